// Round 6
// baseline (214.395 us; speedup 1.0000x reference)
//
#include <hip/hip_runtime.h>
#include <hip/hip_bf16.h>
#include <cstdint>
#include <cstddef>

// ---------------------------------------------------------------------------
// GraphHeterogenousCrossAttention — fused main path, f32 I/O, round 6
//
// Math (only the i=2 / graph / T=1 hetero branch matters):
//   Q   = nf @ Wnq + bnq          (Wnq = W_node@Wq folded, K=128)
//   q   = per-32-col-head softmax(Q)
//   P   = q + v * s/max(s,1e-8),  s = dot(q_head, k_head)
//   out = P @ W_out + b_out
//
// Round-6 changes vs round 5 (55 us, Occ 32%, latency-bound):
//  * 32-row tiles: LDS 16.9 KB -> 8 blocks/CU, 32 waves/CU (was 4/16),
//    grid 2048 staggers HBM bursts across blocks. launch_bounds(256,8)
//    holds VGPR <= 64.
//  * k-softmax hoisted to setup (per-column constant): kvec read from L2,
//    no per-block softmax loop, no kl/kv LDS.
//  * W B-fragments remain direct global->VGPR (L2-resident), K-loops
//    barrier-free; 3 __syncthreads per block.
// ---------------------------------------------------------------------------

typedef __attribute__((ext_vector_type(8))) short short8;
typedef __attribute__((ext_vector_type(4))) float floatx4;

using bf16 = __hip_bfloat16;

static constexpr int Mrows = 65536;   // B*N
static constexpr int Lcols = 256;

static __device__ __forceinline__ short f2bs(float x) {
  bf16 h = __float2bfloat16(x);
  return *reinterpret_cast<short*>(&h);
}

// ---------------------------------------------------------------------------
// Merged setup, grid = 520 blocks x 256 threads:
//  blocks [0,256):   wnq_t[j*128 + r] = bf16(sum_l W_node[r,l] Wq[l,j]), j=b
//  blocks [256,512): wto_t[c*256 + r] = bf16(W_out[r,c]),               r=b-256
//  blocks [512,520): head h=b-512: kvec (softmaxed), vvec, bnq for its 32 cols
__global__ void k_setup(const float* __restrict__ W_node,
                        const float* __restrict__ Wq,
                        const float* __restrict__ W_out,
                        const float* __restrict__ energy,
                        const float* __restrict__ W_graph,
                        const float* __restrict__ b_graph,
                        const float* __restrict__ Wk,
                        const float* __restrict__ bk,
                        const float* __restrict__ Wv,
                        const float* __restrict__ bv,
                        const float* __restrict__ b_node,
                        const float* __restrict__ bq,
                        short* __restrict__ wnq_t,
                        short* __restrict__ wto_t,
                        float* __restrict__ kvec,
                        float* __restrict__ vvec,
                        float* __restrict__ bnq) {
  const int b = blockIdx.x;
  const int t = threadIdx.x;

  if (b < 256) {
    // ---- Wnq fold (transposed store) ----
    __shared__ float wqc[256];
    const int j = b;
    wqc[t] = Wq[t * 256 + j];
    __syncthreads();
    if (t < 128) {
      const float* wr = W_node + t * 256;
      float acc = 0.f;
#pragma unroll 8
      for (int l = 0; l < 256; ++l) acc += wr[l] * wqc[l];
      wnq_t[j * 128 + t] = f2bs(acc);
    }
  } else if (b < 512) {
    // ---- W_out transpose ----
    const int r = b - 256;
    wto_t[t * 256 + r] = f2bs(W_out[r * 256 + t]);
  } else {
    // ---- head h: kl/v/bnq for cols [32h, 32h+32), then k-softmax ----
    __shared__ float ev[32];
    __shared__ float lg[256];
    __shared__ float r0[256], r1[256], r2[256];
    __shared__ float klh[32];
    const int h = b - 512;
    if (t < 32) ev[t] = energy[t];
    __syncthreads();

    // lg[d] = b_graph[d] + energy @ W_graph[:,d]   (d = t)
    {
      float lgd = b_graph[t];
#pragma unroll
      for (int e = 0; e < 32; ++e) lgd += ev[e] * W_graph[e * 256 + t];
      lg[t] = lgd;
    }
    __syncthreads();

    const int g = t >> 5;          // d-group 0..7
    const int c = t & 31;          // col within head
    const int j = h * 32 + c;      // global col
    float p0 = 0.f, p1 = 0.f, p2 = 0.f;
#pragma unroll
    for (int i = 0; i < 32; ++i) {
      const int d = g * 32 + i;
      const float l = lg[d];
      p0 += l * Wk[2 * 65536 + d * 256 + j];
      p1 += l * Wv[2 * 65536 + d * 256 + j];
      p2 += b_node[d] * Wq[d * 256 + j];
    }
    r0[t] = p0; r1[t] = p1; r2[t] = p2;
    __syncthreads();
    if (t < 32) {
      float s0 = 0.f, s1 = 0.f, s2 = 0.f;
#pragma unroll
      for (int gg = 0; gg < 8; ++gg) {
        s0 += r0[gg * 32 + c]; s1 += r1[gg * 32 + c]; s2 += r2[gg * 32 + c];
      }
      klh[c] = s0 + bk[512 + j];
      vvec[j] = s1 + bv[512 + j];
      bnq[j]  = s2 + bq[j];
    }
    __syncthreads();
    if (t < 32) {
      float mx = -1e30f;
#pragma unroll
      for (int i = 0; i < 32; ++i) mx = fmaxf(mx, klh[i]);
      float s = 0.f;
#pragma unroll
      for (int i = 0; i < 32; ++i) s += __expf(klh[i] - mx);
      kvec[j] = __expf(klh[c] - mx) / s;
    }
  }
}

// ---------------------------------------------------------------------------
// Fused: Q-GEMM (K=128) -> per-head softmax + linear-attn -> out-GEMM (K=256)
// Block: 256 threads (4 waves), tile 32 rows x 256 cols; wave w owns cols
// [64w,64w+64) as 2x4 frags of 16x16x32.  A and P live in LDS (union);
// W B-frags direct global->VGPR (L2-resident).  3 __syncthreads.  grid=M/32.
// LDS 16.9 KB -> 8 blocks/CU; launch_bounds(256,8) caps VGPR at 64 for
// 32 waves/CU.
__global__ __launch_bounds__(256, 8)
void k_fused(const float* __restrict__ nf,
             const short* __restrict__ wnq,    // [256 j][128 k] bf16 bits
             const short* __restrict__ wto,    // [256 j][256 k] bf16 bits
             const float* __restrict__ bnq,
             const float* __restrict__ kvec,
             const float* __restrict__ vvec,
             const float* __restrict__ b_out,
             float* __restrict__ out) {
  constexpr int AS_STR = 136;            // A row stride (shorts)
  constexpr int PS_STR = 264;            // P row stride (shorts)
  __shared__ short smem[32 * PS_STR];    // 16896 B (A uses first 8704 B)

  const int t = threadIdx.x;
  const int lane = t & 63;
  const int l15 = lane & 15;
  const int lhi = lane >> 4;             // quad 0..3
  const int cw = (t >> 6) * 64;          // wave col base
  const int rowBase = blockIdx.x * 32;

  // ---- stage A (32 rows x 128 k, f32 -> bf16), once ----
  {
    const int row = t >> 3;
    const int c0 = (t & 7) << 4;         // 0..112 step 16
    const float* src = nf + (size_t)(rowBase + row) * 128 + c0;
    short tmp[16];
#pragma unroll
    for (int i = 0; i < 4; ++i) {
      float4 f = *(const float4*)(src + i * 4);
      tmp[i * 4 + 0] = f2bs(f.x); tmp[i * 4 + 1] = f2bs(f.y);
      tmp[i * 4 + 2] = f2bs(f.z); tmp[i * 4 + 3] = f2bs(f.w);
    }
    *(short8*)(&smem[row * AS_STR + c0]) = *(short8*)(&tmp[0]);
    *(short8*)(&smem[row * AS_STR + c0 + 8]) = *(short8*)(&tmp[8]);
  }
  __syncthreads();                       // (1) A visible

  floatx4 acc[2][4];
#pragma unroll
  for (int m = 0; m < 2; ++m)
#pragma unroll
    for (int n = 0; n < 4; ++n) acc[m][n] = (floatx4){0.f, 0.f, 0.f, 0.f};

  // ---- phase 1: Q = A @ Wnq, K=128, B-frags direct from global (L2) ----
  {
    const short* wb = wnq + (cw + l15) * 128 + lhi * 8;
#pragma unroll
    for (int kc = 0; kc < 4; ++kc) {
      short8 af[2], bfv[4];
#pragma unroll
      for (int n = 0; n < 4; ++n)
        bfv[n] = *(const short8*)(wb + n * 16 * 128 + kc * 32);
#pragma unroll
      for (int m = 0; m < 2; ++m)
        af[m] = *(const short8*)(&smem[(m * 16 + l15) * AS_STR + kc * 32 + lhi * 8]);
#pragma unroll
      for (int m = 0; m < 2; ++m)
#pragma unroll
        for (int n = 0; n < 4; ++n)
          acc[m][n] = __builtin_amdgcn_mfma_f32_16x16x32_bf16(af[m], bfv[n],
                                                              acc[m][n], 0, 0, 0);
    }
  }
  __syncthreads();                       // (2) A reads done; P may overwrite

  // ---- epilogue 1: softmax + q + v*ratio -> P (bf16, LDS) ----
  // C/D layout: col = lane&15, row = (lane>>4)*4 + reg.  Logits O(1):
  // exp without max-subtraction is f32-safe (validated r3-r5, absmax .0156).
#pragma unroll
  for (int tt = 0; tt < 2; ++tt) {
    const int col0 = cw + tt * 32 + l15;
    const int col1 = col0 + 16;
    const float b0 = bnq[col0], b1 = bnq[col1];
    const float k0v = kvec[col0], k1v = kvec[col1];
    const float v0v = vvec[col0], v1v = vvec[col1];
#pragma unroll
    for (int m = 0; m < 2; ++m) {
      const int row0 = m * 16 + lhi * 4;
#pragma unroll
      for (int r = 0; r < 4; ++r) {
        float e0 = __expf(acc[m][2 * tt][r] + b0);
        float e1 = __expf(acc[m][2 * tt + 1][r] + b1);
        float s = e0 + e1;
        float du = e0 * k0v + e1 * k1v;
#pragma unroll
        for (int msk = 1; msk <= 8; msk <<= 1) {
          s += __shfl_xor(s, msk);
          du += __shfl_xor(du, msk);
        }
        float inv = 1.0f / s;
        float d = du * inv;
        float ratio = d / fmaxf(d, 1e-8f);
        smem[(row0 + r) * PS_STR + col0] = f2bs(e0 * inv + v0v * ratio);
        smem[(row0 + r) * PS_STR + col1] = f2bs(e1 * inv + v1v * ratio);
      }
    }
  }
#pragma unroll
  for (int m = 0; m < 2; ++m)
#pragma unroll
    for (int n = 0; n < 4; ++n) acc[m][n] = (floatx4){0.f, 0.f, 0.f, 0.f};
  __syncthreads();                       // (3) P visible to all waves

  // ---- phase 2: out = P @ W_out, K=256, B-frags direct from global ----
  {
    const short* wb = wto + (cw + l15) * 256 + lhi * 8;
#pragma unroll
    for (int kc = 0; kc < 8; ++kc) {
      short8 af[2], bfv[4];
#pragma unroll
      for (int n = 0; n < 4; ++n)
        bfv[n] = *(const short8*)(wb + n * 16 * 256 + kc * 32);
#pragma unroll
      for (int m = 0; m < 2; ++m)
        af[m] = *(const short8*)(&smem[(m * 16 + l15) * PS_STR + kc * 32 + lhi * 8]);
#pragma unroll
      for (int m = 0; m < 2; ++m)
#pragma unroll
        for (int n = 0; n < 4; ++n)
          acc[m][n] = __builtin_amdgcn_mfma_f32_16x16x32_bf16(af[m], bfv[n],
                                                              acc[m][n], 0, 0, 0);
    }
  }

  // ---- epilogue 2: + b_out, f32 store ----
#pragma unroll
  for (int n = 0; n < 4; ++n) {
    const int col = cw + n * 16 + l15;
    const float bb = b_out[col];
#pragma unroll
    for (int m = 0; m < 2; ++m) {
      const int row0 = rowBase + m * 16 + lhi * 4;
#pragma unroll
      for (int r = 0; r < 4; ++r)
        out[(size_t)(row0 + r) * Lcols + col] = acc[m][n][r] + bb;
    }
  }
}

// ---------------------------------------------------------------------------
extern "C" void kernel_launch(void* const* d_in, const int* in_sizes, int n_in,
                              void* d_out, int out_size, void* d_ws, size_t ws_size,
                              hipStream_t stream) {
  const float* node_features = (const float*)d_in[0];
  // d_in[1] edge_features: dead code
  const float* energy  = (const float*)d_in[2];
  const float* W_node  = (const float*)d_in[3];
  const float* b_node  = (const float*)d_in[4];
  // d_in[5,6] W_edge/b_edge: dead code
  const float* W_graph = (const float*)d_in[7];
  const float* b_graph = (const float*)d_in[8];
  const float* Wq      = (const float*)d_in[9];
  const float* bq      = (const float*)d_in[10];
  const float* Wk      = (const float*)d_in[11];
  const float* bk      = (const float*)d_in[12];
  const float* Wv      = (const float*)d_in[13];
  const float* bv      = (const float*)d_in[14];
  const float* W_out   = (const float*)d_in[15];
  const float* b_out   = (const float*)d_in[16];

  // workspace: tables only (< 256 KB)
  char* ws = (char*)d_ws;
  short* wnq_t = (short*)(ws);                  // 256*128*2 = 65536 B
  short* wto_t = (short*)(ws + 65536);          // 256*256*2 = 131072 B
  float* kvec  = (float*)(ws + 196608);         // 1 KB
  float* vvec  = (float*)(ws + 197632);         // 1 KB
  float* bnq   = (float*)(ws + 198656);         // 1 KB

  k_setup<<<dim3(520), dim3(256), 0, stream>>>(
      W_node, Wq, W_out, energy, W_graph, b_graph, Wk, bk, Wv, bv,
      b_node, bq, wnq_t, wto_t, kvec, vvec, bnq);

  k_fused<<<dim3(Mrows / 32), dim3(256), 0, stream>>>(
      node_features, wnq_t, wto_t, bnq, kvec, vvec, b_out, (float*)d_out);
}

// Round 7
// 190.105 us; speedup vs baseline: 1.1278x; 1.1278x over previous
//
#include <hip/hip_runtime.h>
#include <hip/hip_bf16.h>
#include <cstdint>
#include <cstddef>

// ---------------------------------------------------------------------------
// GraphHeterogenousCrossAttention — fused main path, f32 I/O, round 7
//
// Math (only the i=2 / graph / T=1 hetero branch matters):
//   Q   = nf @ Wnq + bnq          (Wnq = W_node@Wq folded, K=128)
//   q   = per-32-col-head softmax(Q)
//   P   = q + v                   (ratio = d/max(d,1e-8) == 1: d >= min(q)
//                                  >= e^-spread/32 >> 1e-8 w.p. 1-1e-27)
//   out = P @ W_out + b_out
//
// Round-7 vs round 5 (55 us) / round 6 (72 us, regression):
//  * 64-row tiles restored (r6's 32-row tiles raised hbm_bytes 93->119 MB;
//    time tracks bytes at ~1.7 TB/s -> store efficiency is the limiter).
//  * Output staged through LDS (f32, stride 260) in two 32-row chunks and
//    stored as per-wave contiguous 1 KB dwordx4 bursts (r5/r6 did 4B
//    col-strided scatter -> 64B segments, write amplification).
//  * ratio==1 removes the d shuffle chain (4 of 8 shfl per element) and
//    kvec from the hot kernel.
//  * W B-frags remain direct global->VGPR (L2-resident), K-loops barrier-free.
// ---------------------------------------------------------------------------

typedef __attribute__((ext_vector_type(8))) short short8;
typedef __attribute__((ext_vector_type(4))) float floatx4;

using bf16 = __hip_bfloat16;

static constexpr int Mrows = 65536;   // B*N
static constexpr int Lcols = 256;

static __device__ __forceinline__ short f2bs(float x) {
  bf16 h = __float2bfloat16(x);
  return *reinterpret_cast<short*>(&h);
}

// ---------------------------------------------------------------------------
// Merged setup, grid = 520 blocks x 256 threads:
//  blocks [0,256):   wnq_t[j*128 + r] = bf16(sum_l W_node[r,l] Wq[l,j]), j=b
//  blocks [256,512): wto_t[c*256 + r] = bf16(W_out[r,c]),               r=b-256
//  blocks [512,520): head h=b-512: vvec, bnq for its 32 cols
__global__ void k_setup(const float* __restrict__ W_node,
                        const float* __restrict__ Wq,
                        const float* __restrict__ W_out,
                        const float* __restrict__ energy,
                        const float* __restrict__ W_graph,
                        const float* __restrict__ b_graph,
                        const float* __restrict__ Wk,
                        const float* __restrict__ bk,
                        const float* __restrict__ Wv,
                        const float* __restrict__ bv,
                        const float* __restrict__ b_node,
                        const float* __restrict__ bq,
                        short* __restrict__ wnq_t,
                        short* __restrict__ wto_t,
                        float* __restrict__ vvec,
                        float* __restrict__ bnq) {
  const int b = blockIdx.x;
  const int t = threadIdx.x;

  if (b < 256) {
    // ---- Wnq fold (transposed store) ----
    __shared__ float wqc[256];
    const int j = b;
    wqc[t] = Wq[t * 256 + j];
    __syncthreads();
    if (t < 128) {
      const float* wr = W_node + t * 256;
      float acc = 0.f;
#pragma unroll 8
      for (int l = 0; l < 256; ++l) acc += wr[l] * wqc[l];
      wnq_t[j * 128 + t] = f2bs(acc);
    }
  } else if (b < 512) {
    // ---- W_out transpose ----
    const int r = b - 256;
    wto_t[t * 256 + r] = f2bs(W_out[r * 256 + t]);
  } else {
    // ---- head h: vvec, bnq for cols [32h, 32h+32) ----
    __shared__ float ev[32];
    __shared__ float lg[256];
    __shared__ float r1[256], r2[256];
    const int h = b - 512;
    if (t < 32) ev[t] = energy[t];
    __syncthreads();

    // lg[d] = b_graph[d] + energy @ W_graph[:,d]   (d = t)
    {
      float lgd = b_graph[t];
#pragma unroll
      for (int e = 0; e < 32; ++e) lgd += ev[e] * W_graph[e * 256 + t];
      lg[t] = lgd;
    }
    __syncthreads();

    const int g = t >> 5;          // d-group 0..7
    const int c = t & 31;          // col within head
    const int j = h * 32 + c;      // global col
    float p1 = 0.f, p2 = 0.f;
#pragma unroll
    for (int i = 0; i < 32; ++i) {
      const int d = g * 32 + i;
      p1 += lg[d] * Wv[2 * 65536 + d * 256 + j];
      p2 += b_node[d] * Wq[d * 256 + j];
    }
    r1[t] = p1; r2[t] = p2;
    __syncthreads();
    if (t < 32) {
      float s1 = 0.f, s2 = 0.f;
#pragma unroll
      for (int gg = 0; gg < 8; ++gg) {
        s1 += r1[gg * 32 + c]; s2 += r2[gg * 32 + c];
      }
      vvec[j] = s1 + bv[512 + j];
      bnq[j]  = s2 + bq[j];
    }
  }
}

// ---------------------------------------------------------------------------
// Fused: Q-GEMM (K=128) -> per-head softmax + v -> out-GEMM (K=256)
// Block: 256 threads (4 waves), tile 64 rows x 256 cols; wave w owns cols
// [64w,64w+64) as 4x4 frags of 16x16x32.  A, P, and the f32 out-bounce tile
// all share one LDS union; W B-frags load direct global->VGPR (L2-resident),
// K-loops barrier-free.  grid = M/64.
__global__ __launch_bounds__(256, 4)
void k_fused(const float* __restrict__ nf,
             const short* __restrict__ wnq,    // [256 j][128 k] bf16 bits
             const short* __restrict__ wto,    // [256 j][256 k] bf16 bits
             const float* __restrict__ bnq,
             const float* __restrict__ vvec,
             const float* __restrict__ b_out,
             float* __restrict__ out) {
  constexpr int AS_STR = 136;            // A row stride (shorts), 272 B
  constexpr int PS_STR = 264;            // P row stride (shorts), 528 B
  constexpr int FO_STR = 260;            // out-bounce row stride (floats), 1040 B
  __shared__ short smem[64 * PS_STR];    // 33792 B union (A: first 17408 B;
                                         // f32 bounce: 32*260*4 = 33280 B)
  float* fsm = (float*)smem;

  const int t = threadIdx.x;
  const int lane = t & 63;
  const int l15 = lane & 15;
  const int lhi = lane >> 4;             // quad 0..3
  const int cw = (t >> 6) * 64;          // wave col base
  const int rowBase = blockIdx.x * 64;

  // ---- stage A (64 rows x 128 k, f32 -> bf16), once ----
  {
    const int row = t >> 2;
    const int c0 = (t & 3) << 5;         // 0,32,64,96
    const float* src = nf + (size_t)(rowBase + row) * 128 + c0;
    short tmp[32];
#pragma unroll
    for (int i = 0; i < 8; ++i) {
      float4 f = *(const float4*)(src + i * 4);
      tmp[i * 4 + 0] = f2bs(f.x); tmp[i * 4 + 1] = f2bs(f.y);
      tmp[i * 4 + 2] = f2bs(f.z); tmp[i * 4 + 3] = f2bs(f.w);
    }
#pragma unroll
    for (int i = 0; i < 4; ++i)
      *(short8*)(&smem[row * AS_STR + c0 + i * 8]) = *(short8*)(&tmp[i * 8]);
  }
  __syncthreads();                       // (1) A visible

  floatx4 acc[4][4];
#pragma unroll
  for (int m = 0; m < 4; ++m)
#pragma unroll
    for (int n = 0; n < 4; ++n) acc[m][n] = (floatx4){0.f, 0.f, 0.f, 0.f};

  // ---- phase 1: Q = A @ Wnq, K=128, B-frags direct from global (L2) ----
  {
    const short* wb = wnq + (cw + l15) * 128 + lhi * 8;
#pragma unroll
    for (int kc = 0; kc < 4; ++kc) {
      short8 af[4], bfv[4];
#pragma unroll
      for (int n = 0; n < 4; ++n)
        bfv[n] = *(const short8*)(wb + n * 16 * 128 + kc * 32);
#pragma unroll
      for (int m = 0; m < 4; ++m)
        af[m] = *(const short8*)(&smem[(m * 16 + l15) * AS_STR + kc * 32 + lhi * 8]);
#pragma unroll
      for (int m = 0; m < 4; ++m)
#pragma unroll
        for (int n = 0; n < 4; ++n)
          acc[m][n] = __builtin_amdgcn_mfma_f32_16x16x32_bf16(af[m], bfv[n],
                                                              acc[m][n], 0, 0, 0);
    }
  }
  __syncthreads();                       // (2) A reads done; P may overwrite

  // ---- epilogue 1: per-head softmax + v -> P (bf16, LDS) ----
  // C/D layout: col = lane&15, row = (lane>>4)*4 + reg.  Logits O(1):
  // exp without max-subtraction is f32-safe (validated r3-r6).
#pragma unroll
  for (int tt = 0; tt < 2; ++tt) {
    const int col0 = cw + tt * 32 + l15;
    const int col1 = col0 + 16;
    const float b0 = bnq[col0], b1 = bnq[col1];
    const float v0v = vvec[col0], v1v = vvec[col1];
#pragma unroll
    for (int m = 0; m < 4; ++m) {
      const int row0 = m * 16 + lhi * 4;
#pragma unroll
      for (int r = 0; r < 4; ++r) {
        float e0 = __expf(acc[m][2 * tt][r] + b0);
        float e1 = __expf(acc[m][2 * tt + 1][r] + b1);
        float s = e0 + e1;
#pragma unroll
        for (int msk = 1; msk <= 8; msk <<= 1) s += __shfl_xor(s, msk);
        float inv = 1.0f / s;
        smem[(row0 + r) * PS_STR + col0] = f2bs(e0 * inv + v0v);
        smem[(row0 + r) * PS_STR + col1] = f2bs(e1 * inv + v1v);
      }
    }
  }
#pragma unroll
  for (int m = 0; m < 4; ++m)
#pragma unroll
    for (int n = 0; n < 4; ++n) acc[m][n] = (floatx4){0.f, 0.f, 0.f, 0.f};
  __syncthreads();                       // (3) P visible to all waves

  // ---- phase 2: out = P @ W_out, K=256, B-frags direct from global ----
  {
    const short* wb = wto + (cw + l15) * 256 + lhi * 8;
#pragma unroll
    for (int kc = 0; kc < 8; ++kc) {
      short8 af[4], bfv[4];
#pragma unroll
      for (int n = 0; n < 4; ++n)
        bfv[n] = *(const short8*)(wb + n * 16 * 256 + kc * 32);
#pragma unroll
      for (int m = 0; m < 4; ++m)
        af[m] = *(const short8*)(&smem[(m * 16 + l15) * PS_STR + kc * 32 + lhi * 8]);
#pragma unroll
      for (int m = 0; m < 4; ++m)
#pragma unroll
        for (int n = 0; n < 4; ++n)
          acc[m][n] = __builtin_amdgcn_mfma_f32_16x16x32_bf16(af[m], bfv[n],
                                                              acc[m][n], 0, 0, 0);
    }
  }

  // ---- epilogue 2: bias, bounce through LDS (f32), coalesced dwordx4 out ----
  float bb[4];
#pragma unroll
  for (int n = 0; n < 4; ++n) bb[n] = b_out[cw + n * 16 + l15];

#pragma unroll
  for (int c = 0; c < 2; ++c) {
    __syncthreads();                     // c=0: all P reads done; c=1: chunk-0
                                         // LDS reads done before overwrite
#pragma unroll
    for (int mm = 0; mm < 2; ++mm) {
      const int m = c * 2 + mm;
#pragma unroll
      for (int n = 0; n < 4; ++n) {
        const int col = cw + n * 16 + l15;
        const int row0 = mm * 16 + lhi * 4;
#pragma unroll
        for (int r = 0; r < 4; ++r)
          fsm[(row0 + r) * FO_STR + col] = acc[m][n][r] + bb[n];
      }
    }
    __syncthreads();
    // cooperative store: 32 rows x 256 f32 = 2048 float4, 8 per thread;
    // each wave stores contiguous 1 KB bursts.
#pragma unroll
    for (int i = 0; i < 8; ++i) {
      const int f = i * 256 + t;
      const int row = f >> 6;
      const int c4 = (f & 63) << 2;
      float4 vv = *(const float4*)(&fsm[row * FO_STR + c4]);
      *(float4*)(&out[(size_t)(rowBase + c * 32 + row) * Lcols + c4]) = vv;
    }
  }
}

// ---------------------------------------------------------------------------
extern "C" void kernel_launch(void* const* d_in, const int* in_sizes, int n_in,
                              void* d_out, int out_size, void* d_ws, size_t ws_size,
                              hipStream_t stream) {
  const float* node_features = (const float*)d_in[0];
  // d_in[1] edge_features: dead code
  const float* energy  = (const float*)d_in[2];
  const float* W_node  = (const float*)d_in[3];
  const float* b_node  = (const float*)d_in[4];
  // d_in[5,6] W_edge/b_edge: dead code
  const float* W_graph = (const float*)d_in[7];
  const float* b_graph = (const float*)d_in[8];
  const float* Wq      = (const float*)d_in[9];
  const float* bq      = (const float*)d_in[10];
  const float* Wk      = (const float*)d_in[11];
  const float* bk      = (const float*)d_in[12];
  const float* Wv      = (const float*)d_in[13];
  const float* bv      = (const float*)d_in[14];
  const float* W_out   = (const float*)d_in[15];
  const float* b_out   = (const float*)d_in[16];

  // workspace: tables only (< 256 KB)
  char* ws = (char*)d_ws;
  short* wnq_t = (short*)(ws);                  // 256*128*2 = 65536 B
  short* wto_t = (short*)(ws + 65536);          // 256*256*2 = 131072 B
  float* vvec  = (float*)(ws + 196608);         // 1 KB
  float* bnq   = (float*)(ws + 197632);         // 1 KB

  k_setup<<<dim3(520), dim3(256), 0, stream>>>(
      W_node, Wq, W_out, energy, W_graph, b_graph, Wk, bk, Wv, bv,
      b_node, bq, wnq_t, wto_t, vvec, bnq);

  k_fused<<<dim3(Mrows / 64), dim3(256), 0, stream>>>(
      node_features, wnq_t, wto_t, bnq, vvec, b_out, (float*)d_out);
}